// Round 1
// baseline (1069.994 us; speedup 1.0000x reference)
//
#include <hip/hip_runtime.h>

// ---------------------------------------------------------------------------
// Problem constants: B=8, N=4096 (64x64 image), DIM=768, HEADS=12, HEAD_DIM=64
// EXP=2 -> EDIM=1536, expanded heads = 24.
// ---------------------------------------------------------------------------
#define NB 8
#define NTOK 4096
#define CDIM 768
#define EDIM 1536
#define NHEADS 12
#define HD 64
#define TOTTOK (NB * NTOK)          // 32768

typedef float floatx4 __attribute__((ext_vector_type(4)));
typedef __bf16 bf16x8 __attribute__((ext_vector_type(8)));

// ---------------------------------------------------------------------------
// fp32 -> bf16 elementwise convert (x)
// ---------------------------------------------------------------------------
__global__ __launch_bounds__(256) void f32_to_bf16_kernel(
    const float* __restrict__ in, __bf16* __restrict__ out, long n) {
  long i = ((long)blockIdx.x * 256 + threadIdx.x) * 4;
  if (i >= n) return;
  float4 f = *(const float4*)(in + i);
  alignas(8) __bf16 h[4];
  h[0] = (__bf16)f.x; h[1] = (__bf16)f.y; h[2] = (__bf16)f.z; h[3] = (__bf16)f.w;
  *(unsigned long long*)(out + i) = *(const unsigned long long*)h;
}

// ---------------------------------------------------------------------------
// W (K x N fp32, row-major) -> Wt (N x K bf16, row-major)
// grid: (N/32, K/32), block 256
// ---------------------------------------------------------------------------
__global__ __launch_bounds__(256) void transpose_w_kernel(
    const float* __restrict__ W, __bf16* __restrict__ Wt, int K, int N) {
  __shared__ float tile[32][33];
  int nb = blockIdx.x * 32, kb = blockIdx.y * 32;
  int tx = threadIdx.x & 31, ty = threadIdx.x >> 5;  // ty 0..7
  #pragma unroll
  for (int i = ty; i < 32; i += 8)
    tile[i][tx] = W[(long)(kb + i) * N + nb + tx];
  __syncthreads();
  #pragma unroll
  for (int i = ty; i < 32; i += 8)
    Wt[(long)(nb + i) * K + kb + tx] = (__bf16)tile[tx][i];
}

// ---------------------------------------------------------------------------
// Generic bf16 MFMA GEMM: C(MxN) = A(MxK,bf16) @ Bt(NxK,bf16)^T
// block 256 = 4 waves; block tile 128x128; wave tile 64x64; acc 4x4 of 16x16.
// out_f32 != 0: C fp32 with bias add; else C bf16, no bias.
// grid: (N/128, M/128)
// ---------------------------------------------------------------------------
__global__ __launch_bounds__(256) void gemm_bf16_kernel(
    const __bf16* __restrict__ A, const __bf16* __restrict__ Bt,
    void* __restrict__ C, const float* __restrict__ bias,
    int M, int N, int K, int out_f32) {
  __shared__ __bf16 As[128 * 40];
  __shared__ __bf16 Bs[128 * 40];
  const int tid = threadIdx.x;
  const long m0 = (long)blockIdx.y * 128;
  const int n0 = blockIdx.x * 128;
  const int wave = tid >> 6, lane = tid & 63;
  const int wm = (wave >> 1) * 64, wn = (wave & 1) * 64;
  const int sr = tid >> 2, sk = (tid & 3) * 8;

  floatx4 acc[4][4] = {};

  const __bf16* Ar0 = A + (m0 + sr) * (long)K + sk;
  const __bf16* Ar1 = Ar0 + 64 * (long)K;
  const __bf16* Br0 = Bt + ((long)n0 + sr) * (long)K + sk;
  const __bf16* Br1 = Br0 + 64 * (long)K;

  const int fr = lane & 15, fk = (lane >> 4) * 8;

  for (int k0 = 0; k0 < K; k0 += 32) {
    __syncthreads();
    *(uint4*)&As[sr * 40 + sk]        = *(const uint4*)(Ar0 + k0);
    *(uint4*)&As[(sr + 64) * 40 + sk] = *(const uint4*)(Ar1 + k0);
    *(uint4*)&Bs[sr * 40 + sk]        = *(const uint4*)(Br0 + k0);
    *(uint4*)&Bs[(sr + 64) * 40 + sk] = *(const uint4*)(Br1 + k0);
    __syncthreads();
    bf16x8 af[4], bfr[4];
    #pragma unroll
    for (int i = 0; i < 4; ++i)
      af[i] = *(const bf16x8*)&As[(wm + i * 16 + fr) * 40 + fk];
    #pragma unroll
    for (int j = 0; j < 4; ++j)
      bfr[j] = *(const bf16x8*)&Bs[(wn + j * 16 + fr) * 40 + fk];
    #pragma unroll
    for (int i = 0; i < 4; ++i)
      #pragma unroll
      for (int j = 0; j < 4; ++j)
        acc[i][j] = __builtin_amdgcn_mfma_f32_16x16x32_bf16(af[i], bfr[j], acc[i][j], 0, 0, 0);
  }

  const int col = lane & 15, rq = (lane >> 4) * 4;
  #pragma unroll
  for (int i = 0; i < 4; ++i)
    #pragma unroll
    for (int j = 0; j < 4; ++j)
      #pragma unroll
      for (int r = 0; r < 4; ++r) {
        long gm = m0 + wm + i * 16 + rq + r;
        int gn = n0 + wn + j * 16 + col;
        float v = acc[i][j][r];
        if (out_f32)
          ((float*)C)[gm * N + gn] = v + bias[gn];
        else
          ((__bf16*)C)[gm * N + gn] = (__bf16)v;
      }
}

// ---------------------------------------------------------------------------
// softmax over head_dim (64) on the k half of kv, in place.
// one wave per (token-row, head). grid: TOTTOK*NHEADS/4 blocks of 256.
// ---------------------------------------------------------------------------
__global__ __launch_bounds__(256) void softmax64_kernel(__bf16* __restrict__ kv) {
  long gid = (long)blockIdx.x * 4 + (threadIdx.x >> 6);
  int lane = threadIdx.x & 63;
  long row = gid / NHEADS;
  int h = (int)(gid % NHEADS);
  __bf16* p = kv + row * EDIM + h * HD;
  float v = (float)p[lane];
  float mx = v;
  #pragma unroll
  for (int m = 32; m; m >>= 1) mx = fmaxf(mx, __shfl_xor(mx, m));
  float e = __expf(v - mx);
  float s = e;
  #pragma unroll
  for (int m = 32; m; m >>= 1) s += __shfl_xor(s, m);
  p[lane] = (__bf16)(e / s);
}

// ---------------------------------------------------------------------------
// ktv partials: ktv_part[split][b][h][d][e] = sum_{n in split} ks[b,n,h,d]*v[b,n,h,e]
// grid: (4, NHEADS, NB), block 256 (4 waves, each 16 d-rows x 64 e-cols)
// ---------------------------------------------------------------------------
__global__ __launch_bounds__(256) void ktv_kernel(
    const __bf16* __restrict__ kv, float* __restrict__ ktv_part) {
  const int split = blockIdx.x, h = blockIdx.y, b = blockIdx.z;
  __shared__ __bf16 As[64 * 40];  // [d][n_local]
  __shared__ __bf16 Bs[64 * 40];  // [e][n_local]
  const int tid = threadIdx.x, wave = tid >> 6, lane = tid & 63;
  const int sn = tid >> 3;        // 0..31
  const int sc = (tid & 7) * 8;   // 0..56
  const int fr = lane & 15, fk = (lane >> 4) * 8;
  floatx4 acc[4] = {};
  const long rowbase = (long)b * NTOK * EDIM;

  for (int n0 = split * 1024; n0 < split * 1024 + 1024; n0 += 32) {
    __syncthreads();
    const __bf16* krow = kv + rowbase + (long)(n0 + sn) * EDIM + h * HD + sc;
    const __bf16* vrow = krow + CDIM;
    uint4 ku = *(const uint4*)krow;
    uint4 vu = *(const uint4*)vrow;
    const __bf16* kh = (const __bf16*)&ku;
    const __bf16* vh = (const __bf16*)&vu;
    #pragma unroll
    for (int j = 0; j < 8; ++j) {
      As[(sc + j) * 40 + sn] = kh[j];
      Bs[(sc + j) * 40 + sn] = vh[j];
    }
    __syncthreads();
    bf16x8 af = *(const bf16x8*)&As[(wave * 16 + fr) * 40 + fk];
    #pragma unroll
    for (int j = 0; j < 4; ++j) {
      bf16x8 bf_ = *(const bf16x8*)&Bs[(j * 16 + fr) * 40 + fk];
      acc[j] = __builtin_amdgcn_mfma_f32_16x16x32_bf16(af, bf_, acc[j], 0, 0, 0);
    }
  }

  const int col = lane & 15, rq = (lane >> 4) * 4;
  long base = (((long)split * NB + b) * NHEADS + h) * (HD * HD);
  #pragma unroll
  for (int j = 0; j < 4; ++j)
    #pragma unroll
    for (int r = 0; r < 4; ++r)
      ktv_part[base + (wave * 16 + rq + r) * HD + j * 16 + col] = acc[j][r];
}

// ---------------------------------------------------------------------------
// Build expanded ektv (bf16, [b][H][d][e], H in [0,24)) from the 4 partials,
// applying the head-expansion roll on the flattened (h*64+e) axis.
// ---------------------------------------------------------------------------
__global__ __launch_bounds__(256) void ektv_kernel(
    const float* __restrict__ ktv_part, __bf16* __restrict__ ektv) {
  int idx = blockIdx.x * 256 + threadIdx.x;  // < 8*24*64*64 = 786432
  int e = idx & 63;
  int d = (idx >> 6) & 63;
  int H = (idx >> 12) % 24;
  int b = idx / 98304;
  int c = H * 64 + e;
  int cp = (c < CDIM) ? c : (c - CDIM + 32) % CDIM;
  int hs = cp >> 6, es = cp & 63;
  long o = (((long)b * NHEADS + hs) * HD + d) * HD + es;
  float s = 0.f;
  #pragma unroll
  for (int sp = 0; sp < 4; ++sp)
    s += ktv_part[(long)sp * (NB * NHEADS * HD * HD) + o];
  ektv[idx] = (__bf16)s;
}

// ---------------------------------------------------------------------------
// attn: mid[b, n, H*64+e] = scale * sum_d eq[b,H,n,d] * ektv[b,H,d,e]
// eq columns for head H are q columns (qbase..qbase+63) mod 768.
// grid: (NTOK/128, 24, NB), block 256 (4 waves x 32 token rows).
// ---------------------------------------------------------------------------
__global__ __launch_bounds__(256) void attn_kernel(
    const __bf16* __restrict__ q, const __bf16* __restrict__ ektv,
    __bf16* __restrict__ mid) {
  const int tt = blockIdx.x, H = blockIdx.y, b = blockIdx.z;
  __shared__ __bf16 As[128 * 72];  // [n_local][d]
  __shared__ __bf16 Bs[64 * 72];   // [e][d]
  const int tid = threadIdx.x, wave = tid >> 6, lane = tid & 63;
  const int qbase = (H < NHEADS) ? H * 64 : (H - NHEADS) * 64 + 32;
  const long n0 = (long)b * NTOK + tt * 128;

  {  // stage A (q slice, handling the circular roll per 8-wide chunk)
    int nl = tid >> 1, d0 = (tid & 1) * 32;
    const __bf16* qrow = q + (n0 + nl) * CDIM;
    #pragma unroll
    for (int cch = 0; cch < 4; ++cch) {
      int d = d0 + cch * 8;
      int c0 = qbase + d;
      if (c0 >= CDIM) c0 -= CDIM;
      *(uint4*)&As[nl * 72 + d] = *(const uint4*)(qrow + c0);
    }
  }
  {  // stage B transposed: Bs[e][d] = ektv[b][H][d][e]
    int e = tid & 63, dch = (tid >> 6) * 16;
    const __bf16* src = ektv + ((long)b * 24 + H) * (HD * HD);
    alignas(16) __bf16 tmp[16];
    #pragma unroll
    for (int j = 0; j < 16; ++j) tmp[j] = src[(dch + j) * 64 + e];
    *(uint4*)&Bs[e * 72 + dch] = *(const uint4*)&tmp[0];
    *(uint4*)&Bs[e * 72 + dch + 8] = *(const uint4*)&tmp[8];
  }
  __syncthreads();

  floatx4 acc[2][4] = {};
  const int fr = lane & 15, fk = (lane >> 4) * 8;
  const int wm = wave * 32;
  #pragma unroll
  for (int kk = 0; kk < 64; kk += 32) {
    bf16x8 af0 = *(const bf16x8*)&As[(wm + fr) * 72 + kk + fk];
    bf16x8 af1 = *(const bf16x8*)&As[(wm + 16 + fr) * 72 + kk + fk];
    #pragma unroll
    for (int j = 0; j < 4; ++j) {
      bf16x8 bf_ = *(const bf16x8*)&Bs[(j * 16 + fr) * 72 + kk + fk];
      acc[0][j] = __builtin_amdgcn_mfma_f32_16x16x32_bf16(af0, bf_, acc[0][j], 0, 0, 0);
      acc[1][j] = __builtin_amdgcn_mfma_f32_16x16x32_bf16(af1, bf_, acc[1][j], 0, 0, 0);
    }
  }

  const int col = lane & 15, rq = (lane >> 4) * 4;
  const float scale = 0.125f;  // HEAD_DIM^-0.5
  #pragma unroll
  for (int i = 0; i < 2; ++i)
    #pragma unroll
    for (int j = 0; j < 4; ++j)
      #pragma unroll
      for (int r = 0; r < 4; ++r) {
        long n = n0 + wm + i * 16 + rq + r;
        mid[n * EDIM + H * 64 + j * 16 + col] = (__bf16)(acc[i][j][r] * scale);
      }
}

// ---------------------------------------------------------------------------
// LePE depthwise 3x3 conv on expanded q (channel c -> q column via roll),
// accumulated into mid (+bias).
// ---------------------------------------------------------------------------
__global__ __launch_bounds__(256) void lepe_kernel(
    const __bf16* __restrict__ q, const float* __restrict__ w_lepe,
    const float* __restrict__ b_lepe, __bf16* __restrict__ mid) {
  long idx = (long)blockIdx.x * 256 + threadIdx.x;  // < TOTTOK * EDIM
  int c = (int)(idx % EDIM);
  long bn = idx / EDIM;
  int n = (int)(bn % NTOK);
  int b = (int)(bn / NTOK);
  int y = n >> 6, x = n & 63;
  int cp = (c < CDIM) ? c : (c - CDIM + 32) % CDIM;
  const __bf16* qb = q + (long)b * NTOK * CDIM + cp;
  float acc = b_lepe[c];
  const float* w = w_lepe + c * 9;
  #pragma unroll
  for (int ky = 0; ky < 3; ++ky) {
    int yy = y + ky - 1;
    if (yy < 0 || yy > 63) continue;
    #pragma unroll
    for (int kx = 0; kx < 3; ++kx) {
      int xx = x + kx - 1;
      if (xx < 0 || xx > 63) continue;
      acc += w[ky * 3 + kx] * (float)qb[(long)(yy * 64 + xx) * CDIM];
    }
  }
  mid[idx] = (__bf16)((float)mid[idx] + acc);
}

// ---------------------------------------------------------------------------
// launch
// ---------------------------------------------------------------------------
extern "C" void kernel_launch(void* const* d_in, const int* in_sizes, int n_in,
                              void* d_out, int out_size, void* d_ws, size_t ws_size,
                              hipStream_t stream) {
  const float* x      = (const float*)d_in[0];
  const float* w_q    = (const float*)d_in[1];
  const float* w_kv   = (const float*)d_in[2];
  const float* w_proj = (const float*)d_in[3];
  const float* b_proj = (const float*)d_in[4];
  const float* w_lepe = (const float*)d_in[5];
  const float* b_lepe = (const float*)d_in[6];
  float* out = (float*)d_out;

  char* ws = (char*)d_ws;
  __bf16* Wt_q  = (__bf16*)ws; ws += (long)CDIM * CDIM * 2;       // 768x768
  __bf16* Wt_kv = (__bf16*)ws; ws += (long)EDIM * CDIM * 2;       // 1536x768 (NxK)
  __bf16* Wt_p  = (__bf16*)ws; ws += (long)CDIM * EDIM * 2;       // 768x1536 (NxK)
  __bf16* xb    = (__bf16*)ws; ws += (long)TOTTOK * CDIM * 2;
  __bf16* qb    = (__bf16*)ws; ws += (long)TOTTOK * CDIM * 2;
  __bf16* kvb   = (__bf16*)ws; ws += (long)TOTTOK * EDIM * 2;     // later aliased as mid
  float*  ktv_part = (float*)ws; ws += (long)4 * NB * NHEADS * HD * HD * 4;
  __bf16* ektv  = (__bf16*)ws; ws += (long)NB * 24 * HD * HD * 2;
  __bf16* mid = kvb;  // alias: kv is dead once ektv is built

  // 1. x -> bf16
  f32_to_bf16_kernel<<<(TOTTOK * CDIM) / (256 * 4), 256, 0, stream>>>(
      x, xb, (long)TOTTOK * CDIM);
  // 2. weight transposes (K x N -> N x K bf16)
  transpose_w_kernel<<<dim3(CDIM / 32, CDIM / 32), 256, 0, stream>>>(w_q, Wt_q, CDIM, CDIM);
  transpose_w_kernel<<<dim3(EDIM / 32, CDIM / 32), 256, 0, stream>>>(w_kv, Wt_kv, CDIM, EDIM);
  transpose_w_kernel<<<dim3(CDIM / 32, EDIM / 32), 256, 0, stream>>>(w_proj, Wt_p, EDIM, CDIM);
  // 3. q = x @ w_q (bf16 out)
  gemm_bf16_kernel<<<dim3(CDIM / 128, TOTTOK / 128), 256, 0, stream>>>(
      xb, Wt_q, qb, nullptr, TOTTOK, CDIM, CDIM, 0);
  // 4. kv = x @ w_kv (bf16 out)
  gemm_bf16_kernel<<<dim3(EDIM / 128, TOTTOK / 128), 256, 0, stream>>>(
      xb, Wt_kv, kvb, nullptr, TOTTOK, EDIM, CDIM, 0);
  // 5. softmax over head_dim on k half, in place
  softmax64_kernel<<<(TOTTOK * NHEADS) / 4, 256, 0, stream>>>(kvb);
  // 6. ktv partials (split-K over tokens)
  ktv_kernel<<<dim3(4, NHEADS, NB), 256, 0, stream>>>(kvb, ktv_part);
  // 7. reduce partials + head-expand -> ektv
  ektv_kernel<<<(NB * 24 * HD * HD) / 256, 256, 0, stream>>>(ktv_part, ektv);
  // 8. attn -> mid (overwrites kv buffer)
  attn_kernel<<<dim3(NTOK / 128, 24, NB), 256, 0, stream>>>(qb, ektv, mid);
  // 9. mid += lepe
  lepe_kernel<<<(long)(TOTTOK)*EDIM / 256, 256, 0, stream>>>(qb, w_lepe, b_lepe, mid);
  // 10. out = mid @ w_proj + b_proj (fp32 out)
  gemm_bf16_kernel<<<dim3(CDIM / 128, TOTTOK / 128), 256, 0, stream>>>(
      mid, Wt_p, out, b_proj, TOTTOK, CDIM, EDIM, 1);
}

// Round 2
// 773.005 us; speedup vs baseline: 1.3842x; 1.3842x over previous
//
#include <hip/hip_runtime.h>

// ---------------------------------------------------------------------------
// Problem constants: B=8, N=4096 (64x64 image), DIM=768, HEADS=12, HEAD_DIM=64
// EXP=2 -> EDIM=1536, expanded heads = 24.
// ---------------------------------------------------------------------------
#define NB 8
#define NTOK 4096
#define CDIM 768
#define EDIM 1536
#define NHEADS 12
#define HD 64
#define TOTTOK (NB * NTOK)          // 32768

typedef float floatx4 __attribute__((ext_vector_type(4)));
typedef __bf16 bf16x8 __attribute__((ext_vector_type(8)));

// ---------------------------------------------------------------------------
// fp32 -> bf16 elementwise convert (x)
// ---------------------------------------------------------------------------
__global__ __launch_bounds__(256) void f32_to_bf16_kernel(
    const float* __restrict__ in, __bf16* __restrict__ out, long n) {
  long i = ((long)blockIdx.x * 256 + threadIdx.x) * 4;
  if (i >= n) return;
  float4 f = *(const float4*)(in + i);
  alignas(8) __bf16 h[4];
  h[0] = (__bf16)f.x; h[1] = (__bf16)f.y; h[2] = (__bf16)f.z; h[3] = (__bf16)f.w;
  *(unsigned long long*)(out + i) = *(const unsigned long long*)h;
}

// ---------------------------------------------------------------------------
// W (K x N fp32, row-major) -> Wt (N x K bf16, row-major)
// grid: (N/32, K/32), block 256
// ---------------------------------------------------------------------------
__global__ __launch_bounds__(256) void transpose_w_kernel(
    const float* __restrict__ W, __bf16* __restrict__ Wt, int K, int N) {
  __shared__ float tile[32][33];
  int nb = blockIdx.x * 32, kb = blockIdx.y * 32;
  int tx = threadIdx.x & 31, ty = threadIdx.x >> 5;  // ty 0..7
  #pragma unroll
  for (int i = ty; i < 32; i += 8)
    tile[i][tx] = W[(long)(kb + i) * N + nb + tx];
  __syncthreads();
  #pragma unroll
  for (int i = ty; i < 32; i += 8)
    Wt[(long)(nb + i) * K + kb + tx] = (__bf16)tile[tx][i];
}

// ---------------------------------------------------------------------------
// Generic bf16 MFMA GEMM: C(MxN) = A(MxK,bf16) @ Bt(NxK,bf16)^T
// block 256 = 4 waves; block tile 128x128; wave tile 64x64; acc 4x4 of 16x16.
// out_f32 != 0: C fp32 with bias add; else C bf16, no bias.
// grid: (N/128, M/128)
// ---------------------------------------------------------------------------
__global__ __launch_bounds__(256) void gemm_bf16_kernel(
    const __bf16* __restrict__ A, const __bf16* __restrict__ Bt,
    void* __restrict__ C, const float* __restrict__ bias,
    int M, int N, int K, int out_f32) {
  __shared__ __bf16 As[128 * 40];
  __shared__ __bf16 Bs[128 * 40];
  const int tid = threadIdx.x;
  const long m0 = (long)blockIdx.y * 128;
  const int n0 = blockIdx.x * 128;
  const int wave = tid >> 6, lane = tid & 63;
  const int wm = (wave >> 1) * 64, wn = (wave & 1) * 64;
  const int sr = tid >> 2, sk = (tid & 3) * 8;

  floatx4 acc[4][4] = {};

  const __bf16* Ar0 = A + (m0 + sr) * (long)K + sk;
  const __bf16* Ar1 = Ar0 + 64 * (long)K;
  const __bf16* Br0 = Bt + ((long)n0 + sr) * (long)K + sk;
  const __bf16* Br1 = Br0 + 64 * (long)K;

  const int fr = lane & 15, fk = (lane >> 4) * 8;

  for (int k0 = 0; k0 < K; k0 += 32) {
    __syncthreads();
    *(uint4*)&As[sr * 40 + sk]        = *(const uint4*)(Ar0 + k0);
    *(uint4*)&As[(sr + 64) * 40 + sk] = *(const uint4*)(Ar1 + k0);
    *(uint4*)&Bs[sr * 40 + sk]        = *(const uint4*)(Br0 + k0);
    *(uint4*)&Bs[(sr + 64) * 40 + sk] = *(const uint4*)(Br1 + k0);
    __syncthreads();
    bf16x8 af[4], bfr[4];
    #pragma unroll
    for (int i = 0; i < 4; ++i)
      af[i] = *(const bf16x8*)&As[(wm + i * 16 + fr) * 40 + fk];
    #pragma unroll
    for (int j = 0; j < 4; ++j)
      bfr[j] = *(const bf16x8*)&Bs[(wn + j * 16 + fr) * 40 + fk];
    #pragma unroll
    for (int i = 0; i < 4; ++i)
      #pragma unroll
      for (int j = 0; j < 4; ++j)
        acc[i][j] = __builtin_amdgcn_mfma_f32_16x16x32_bf16(af[i], bfr[j], acc[i][j], 0, 0, 0);
  }

  const int col = lane & 15, rq = (lane >> 4) * 4;
  #pragma unroll
  for (int i = 0; i < 4; ++i)
    #pragma unroll
    for (int j = 0; j < 4; ++j)
      #pragma unroll
      for (int r = 0; r < 4; ++r) {
        long gm = m0 + wm + i * 16 + rq + r;
        int gn = n0 + wn + j * 16 + col;
        float v = acc[i][j][r];
        if (out_f32)
          ((float*)C)[gm * N + gn] = v + bias[gn];
        else
          ((__bf16*)C)[gm * N + gn] = (__bf16)v;
      }
}

// ---------------------------------------------------------------------------
// softmax over head_dim (64) on the k half of kv, in place.
// one wave per (token-row, head). grid: TOTTOK*NHEADS/4 blocks of 256.
// ---------------------------------------------------------------------------
__global__ __launch_bounds__(256) void softmax64_kernel(__bf16* __restrict__ kv) {
  long gid = (long)blockIdx.x * 4 + (threadIdx.x >> 6);
  int lane = threadIdx.x & 63;
  long row = gid / NHEADS;
  int h = (int)(gid % NHEADS);
  __bf16* p = kv + row * EDIM + h * HD;
  float v = (float)p[lane];
  float mx = v;
  #pragma unroll
  for (int m = 32; m; m >>= 1) mx = fmaxf(mx, __shfl_xor(mx, m));
  float e = __expf(v - mx);
  float s = e;
  #pragma unroll
  for (int m = 32; m; m >>= 1) s += __shfl_xor(s, m);
  p[lane] = (__bf16)(e / s);
}

// ---------------------------------------------------------------------------
// ktv partials: ktv_part[split][b][h][d][e] = sum_{n in split} ks[b,n,h,d]*v[b,n,h,e]
// grid: (4, NHEADS, NB), block 256 (4 waves, each 16 d-rows x 64 e-cols)
// ---------------------------------------------------------------------------
__global__ __launch_bounds__(256) void ktv_kernel(
    const __bf16* __restrict__ kv, float* __restrict__ ktv_part) {
  const int split = blockIdx.x, h = blockIdx.y, b = blockIdx.z;
  __shared__ __bf16 As[64 * 40];  // [d][n_local]
  __shared__ __bf16 Bs[64 * 40];  // [e][n_local]
  const int tid = threadIdx.x, wave = tid >> 6, lane = tid & 63;
  const int sn = tid >> 3;        // 0..31
  const int sc = (tid & 7) * 8;   // 0..56
  const int fr = lane & 15, fk = (lane >> 4) * 8;
  floatx4 acc[4] = {};
  const long rowbase = (long)b * NTOK * EDIM;

  for (int n0 = split * 1024; n0 < split * 1024 + 1024; n0 += 32) {
    __syncthreads();
    const __bf16* krow = kv + rowbase + (long)(n0 + sn) * EDIM + h * HD + sc;
    const __bf16* vrow = krow + CDIM;
    uint4 ku = *(const uint4*)krow;
    uint4 vu = *(const uint4*)vrow;
    const __bf16* kh = (const __bf16*)&ku;
    const __bf16* vh = (const __bf16*)&vu;
    #pragma unroll
    for (int j = 0; j < 8; ++j) {
      As[(sc + j) * 40 + sn] = kh[j];
      Bs[(sc + j) * 40 + sn] = vh[j];
    }
    __syncthreads();
    bf16x8 af = *(const bf16x8*)&As[(wave * 16 + fr) * 40 + fk];
    #pragma unroll
    for (int j = 0; j < 4; ++j) {
      bf16x8 bf_ = *(const bf16x8*)&Bs[(j * 16 + fr) * 40 + fk];
      acc[j] = __builtin_amdgcn_mfma_f32_16x16x32_bf16(af, bf_, acc[j], 0, 0, 0);
    }
  }

  const int col = lane & 15, rq = (lane >> 4) * 4;
  long base = (((long)split * NB + b) * NHEADS + h) * (HD * HD);
  #pragma unroll
  for (int j = 0; j < 4; ++j)
    #pragma unroll
    for (int r = 0; r < 4; ++r)
      ktv_part[base + (wave * 16 + rq + r) * HD + j * 16 + col] = acc[j][r];
}

// ---------------------------------------------------------------------------
// Build expanded ektv (bf16, [b][H][d][e], H in [0,24)) from the 4 partials,
// applying the head-expansion roll on the flattened (h*64+e) axis.
// ---------------------------------------------------------------------------
__global__ __launch_bounds__(256) void ektv_kernel(
    const float* __restrict__ ktv_part, __bf16* __restrict__ ektv) {
  int idx = blockIdx.x * 256 + threadIdx.x;  // < 8*24*64*64 = 786432
  int e = idx & 63;
  int d = (idx >> 6) & 63;
  int H = (idx >> 12) % 24;
  int b = idx / 98304;
  int c = H * 64 + e;
  int cp = (c < CDIM) ? c : (c - CDIM + 32) % CDIM;
  int hs = cp >> 6, es = cp & 63;
  long o = (((long)b * NHEADS + hs) * HD + d) * HD + es;
  float s = 0.f;
  #pragma unroll
  for (int sp = 0; sp < 4; ++sp)
    s += ktv_part[(long)sp * (NB * NHEADS * HD * HD) + o];
  ektv[idx] = (__bf16)s;
}

// ---------------------------------------------------------------------------
// attn: mid[b, n, H*64+e] = scale * sum_d eq[b,H,n,d] * ektv[b,H,d,e]
// eq columns for head H are q columns (qbase..qbase+63) mod 768.
// grid: (NTOK/128, 24, NB), block 256 (4 waves x 32 token rows).
// ---------------------------------------------------------------------------
__global__ __launch_bounds__(256) void attn_kernel(
    const __bf16* __restrict__ q, const __bf16* __restrict__ ektv,
    __bf16* __restrict__ mid) {
  const int tt = blockIdx.x, H = blockIdx.y, b = blockIdx.z;
  __shared__ __bf16 As[128 * 72];  // [n_local][d]
  __shared__ __bf16 Bs[64 * 72];   // [e][d]
  const int tid = threadIdx.x, wave = tid >> 6, lane = tid & 63;
  const int qbase = (H < NHEADS) ? H * 64 : (H - NHEADS) * 64 + 32;
  const long n0 = (long)b * NTOK + tt * 128;

  {  // stage A (q slice, handling the circular roll per 8-wide chunk)
    int nl = tid >> 1, d0 = (tid & 1) * 32;
    const __bf16* qrow = q + (n0 + nl) * CDIM;
    #pragma unroll
    for (int cch = 0; cch < 4; ++cch) {
      int d = d0 + cch * 8;
      int c0 = qbase + d;
      if (c0 >= CDIM) c0 -= CDIM;
      *(uint4*)&As[nl * 72 + d] = *(const uint4*)(qrow + c0);
    }
  }
  {  // stage B transposed: Bs[e][d] = ektv[b][H][d][e]
    int e = tid & 63, dch = (tid >> 6) * 16;
    const __bf16* src = ektv + ((long)b * 24 + H) * (HD * HD);
    alignas(16) __bf16 tmp[16];
    #pragma unroll
    for (int j = 0; j < 16; ++j) tmp[j] = src[(dch + j) * 64 + e];
    *(uint4*)&Bs[e * 72 + dch] = *(const uint4*)&tmp[0];
    *(uint4*)&Bs[e * 72 + dch + 8] = *(const uint4*)&tmp[8];
  }
  __syncthreads();

  floatx4 acc[2][4] = {};
  const int fr = lane & 15, fk = (lane >> 4) * 8;
  const int wm = wave * 32;
  #pragma unroll
  for (int kk = 0; kk < 64; kk += 32) {
    bf16x8 af0 = *(const bf16x8*)&As[(wm + fr) * 72 + kk + fk];
    bf16x8 af1 = *(const bf16x8*)&As[(wm + 16 + fr) * 72 + kk + fk];
    #pragma unroll
    for (int j = 0; j < 4; ++j) {
      bf16x8 bf_ = *(const bf16x8*)&Bs[(j * 16 + fr) * 72 + kk + fk];
      acc[0][j] = __builtin_amdgcn_mfma_f32_16x16x32_bf16(af0, bf_, acc[0][j], 0, 0, 0);
      acc[1][j] = __builtin_amdgcn_mfma_f32_16x16x32_bf16(af1, bf_, acc[1][j], 0, 0, 0);
    }
  }

  const int col = lane & 15, rq = (lane >> 4) * 4;
  const float scale = 0.125f;  // HEAD_DIM^-0.5
  #pragma unroll
  for (int i = 0; i < 2; ++i)
    #pragma unroll
    for (int j = 0; j < 4; ++j)
      #pragma unroll
      for (int r = 0; r < 4; ++r) {
        long n = n0 + wm + i * 16 + rq + r;
        mid[n * EDIM + H * 64 + j * 16 + col] = (__bf16)(acc[i][j][r] * scale);
      }
}

// ---------------------------------------------------------------------------
// LePE depthwise 3x3 conv, tiled through LDS.
// grid: (12 ch-groups of 64 q-channels, 16 y-groups of 4 rows, NB).
// Stages a 6-row x 64-x x 64-ch slab of q (zero-filled halo) and produces
// BOTH expanded duplicates (c and 768+((c+736)%768)) from one set of taps.
// Accumulates into mid (+bias).
// ---------------------------------------------------------------------------
__global__ __launch_bounds__(256) void lepe_kernel(
    const __bf16* __restrict__ q, const float* __restrict__ w_lepe,
    const float* __restrict__ b_lepe, __bf16* __restrict__ mid) {
  __shared__ __bf16 smem[6 * 64 * 64];  // [row][x][ch], 48 KB
  const int g = blockIdx.x, yg = blockIdx.y, b = blockIdx.z;
  const int y0 = yg * 4;
  const int tid = threadIdx.x;

  // load 6 rows (y0-1 .. y0+4), zero-filled out-of-range, uint4 (8 bf16) each
  #pragma unroll
  for (int k = 0; k < 12; ++k) {
    int v = tid + k * 256;            // 0..3071
    int r = v >> 9;                   // row in slab, 0..5
    int rem = v & 511;
    int x = rem >> 3;
    int chv = (rem & 7) * 8;
    int yy = y0 + r - 1;
    uint4 val = {0u, 0u, 0u, 0u};
    if (yy >= 0 && yy < 64)
      val = *(const uint4*)(q + ((long)(b * NTOK + yy * 64 + x)) * CDIM + g * 64 + chv);
    *(uint4*)&smem[r * 4096 + x * 64 + chv] = val;
  }
  __syncthreads();

  const int ch = tid & 63, xg = tid >> 6;
  const int cq = g * 64 + ch;                 // expanded channel (identity half)
  const int c2 = CDIM + ((cq + 736) % CDIM);  // rolled duplicate channel
  float w1[9], w2[9];
  #pragma unroll
  for (int j = 0; j < 9; ++j) {
    w1[j] = w_lepe[cq * 9 + j];
    w2[j] = w_lepe[c2 * 9 + j];
  }
  const float bias1 = b_lepe[cq], bias2 = b_lepe[c2];

  for (int ly = 0; ly < 4; ++ly) {
    for (int i = 0; i < 16; ++i) {
      int x = xg * 16 + i;
      float a1 = bias1, a2 = bias2;
      #pragma unroll
      for (int r = 0; r < 3; ++r) {
        #pragma unroll
        for (int dx = 0; dx < 3; ++dx) {
          int xx = x + dx - 1;
          if (xx < 0 || xx > 63) continue;  // wave-uniform (xg uniform per wave)
          float v = (float)smem[(ly + r) * 4096 + xx * 64 + ch];
          a1 += w1[r * 3 + dx] * v;
          a2 += w2[r * 3 + dx] * v;
        }
      }
      long o = ((long)(b * NTOK + (y0 + ly) * 64 + x)) * EDIM;
      mid[o + cq] = (__bf16)((float)mid[o + cq] + a1);
      mid[o + c2] = (__bf16)((float)mid[o + c2] + a2);
    }
  }
}

// ---------------------------------------------------------------------------
// launch
// ---------------------------------------------------------------------------
extern "C" void kernel_launch(void* const* d_in, const int* in_sizes, int n_in,
                              void* d_out, int out_size, void* d_ws, size_t ws_size,
                              hipStream_t stream) {
  const float* x      = (const float*)d_in[0];
  const float* w_q    = (const float*)d_in[1];
  const float* w_kv   = (const float*)d_in[2];
  const float* w_proj = (const float*)d_in[3];
  const float* b_proj = (const float*)d_in[4];
  const float* w_lepe = (const float*)d_in[5];
  const float* b_lepe = (const float*)d_in[6];
  float* out = (float*)d_out;

  char* ws = (char*)d_ws;
  __bf16* Wt_q  = (__bf16*)ws; ws += (long)CDIM * CDIM * 2;       // 768x768
  __bf16* Wt_kv = (__bf16*)ws; ws += (long)EDIM * CDIM * 2;       // 1536x768 (NxK)
  __bf16* Wt_p  = (__bf16*)ws; ws += (long)CDIM * EDIM * 2;       // 768x1536 (NxK)
  __bf16* xb    = (__bf16*)ws; ws += (long)TOTTOK * CDIM * 2;
  __bf16* qb    = (__bf16*)ws; ws += (long)TOTTOK * CDIM * 2;
  __bf16* kvb   = (__bf16*)ws; ws += (long)TOTTOK * EDIM * 2;     // later aliased as mid
  float*  ktv_part = (float*)ws; ws += (long)4 * NB * NHEADS * HD * HD * 4;
  __bf16* ektv  = (__bf16*)ws; ws += (long)NB * 24 * HD * HD * 2;
  __bf16* mid = kvb;  // alias: kv is dead once ektv is built

  // 1. x -> bf16
  f32_to_bf16_kernel<<<(TOTTOK * CDIM) / (256 * 4), 256, 0, stream>>>(
      x, xb, (long)TOTTOK * CDIM);
  // 2. weight transposes (K x N -> N x K bf16)
  transpose_w_kernel<<<dim3(CDIM / 32, CDIM / 32), 256, 0, stream>>>(w_q, Wt_q, CDIM, CDIM);
  transpose_w_kernel<<<dim3(EDIM / 32, CDIM / 32), 256, 0, stream>>>(w_kv, Wt_kv, CDIM, EDIM);
  transpose_w_kernel<<<dim3(CDIM / 32, EDIM / 32), 256, 0, stream>>>(w_proj, Wt_p, EDIM, CDIM);
  // 3. q = x @ w_q (bf16 out)
  gemm_bf16_kernel<<<dim3(CDIM / 128, TOTTOK / 128), 256, 0, stream>>>(
      xb, Wt_q, qb, nullptr, TOTTOK, CDIM, CDIM, 0);
  // 4. kv = x @ w_kv (bf16 out)
  gemm_bf16_kernel<<<dim3(EDIM / 128, TOTTOK / 128), 256, 0, stream>>>(
      xb, Wt_kv, kvb, nullptr, TOTTOK, EDIM, CDIM, 0);
  // 5. softmax over head_dim on k half, in place
  softmax64_kernel<<<(TOTTOK * NHEADS) / 4, 256, 0, stream>>>(kvb);
  // 6. ktv partials (split-K over tokens)
  ktv_kernel<<<dim3(4, NHEADS, NB), 256, 0, stream>>>(kvb, ktv_part);
  // 7. reduce partials + head-expand -> ektv
  ektv_kernel<<<(NB * 24 * HD * HD) / 256, 256, 0, stream>>>(ktv_part, ektv);
  // 8. attn -> mid (overwrites kv buffer)
  attn_kernel<<<dim3(NTOK / 128, 24, NB), 256, 0, stream>>>(qb, ektv, mid);
  // 9. mid += lepe (tiled, LDS-staged)
  lepe_kernel<<<dim3(12, 16, NB), 256, 0, stream>>>(qb, w_lepe, b_lepe, mid);
  // 10. out = mid @ w_proj + b_proj (fp32 out)
  gemm_bf16_kernel<<<dim3(CDIM / 128, TOTTOK / 128), 256, 0, stream>>>(
      mid, Wt_p, out, b_proj, TOTTOK, CDIM, EDIM, 1);
}

// Round 3
// 706.410 us; speedup vs baseline: 1.5147x; 1.0943x over previous
//
#include <hip/hip_runtime.h>

// ---------------------------------------------------------------------------
// Problem constants: B=8, N=4096 (64x64 image), DIM=768, HEADS=12, HEAD_DIM=64
// EXP=2 -> EDIM=1536, expanded heads = 24.
// ---------------------------------------------------------------------------
#define NB 8
#define NTOK 4096
#define CDIM 768
#define EDIM 1536
#define NHEADS 12
#define HD 64
#define TOTTOK (NB * NTOK)          // 32768

typedef float floatx4 __attribute__((ext_vector_type(4)));
typedef __bf16 bf16x8 __attribute__((ext_vector_type(8)));

// async 16B global -> LDS (lane-contiguous LDS dest: wave base + lane*16)
__device__ __forceinline__ void gld16(const __bf16* g, void* l) {
  __builtin_amdgcn_global_load_lds(
      (const __attribute__((address_space(1))) unsigned int*)g,
      (__attribute__((address_space(3))) unsigned int*)l, 16, 0, 0);
}

// ---------------------------------------------------------------------------
// fp32 -> bf16 elementwise convert (x)
// ---------------------------------------------------------------------------
__global__ __launch_bounds__(256) void f32_to_bf16_kernel(
    const float* __restrict__ in, __bf16* __restrict__ out, long n) {
  long i = ((long)blockIdx.x * 256 + threadIdx.x) * 4;
  if (i >= n) return;
  float4 f = *(const float4*)(in + i);
  alignas(8) __bf16 h[4];
  h[0] = (__bf16)f.x; h[1] = (__bf16)f.y; h[2] = (__bf16)f.z; h[3] = (__bf16)f.w;
  *(unsigned long long*)(out + i) = *(const unsigned long long*)h;
}

// ---------------------------------------------------------------------------
// W (K x N fp32, row-major) -> Wt (N x K bf16, row-major)
// grid: (N/32, K/32), block 256
// ---------------------------------------------------------------------------
__global__ __launch_bounds__(256) void transpose_w_kernel(
    const float* __restrict__ W, __bf16* __restrict__ Wt, int K, int N) {
  __shared__ float tile[32][33];
  int nb = blockIdx.x * 32, kb = blockIdx.y * 32;
  int tx = threadIdx.x & 31, ty = threadIdx.x >> 5;  // ty 0..7
  #pragma unroll
  for (int i = ty; i < 32; i += 8)
    tile[i][tx] = W[(long)(kb + i) * N + nb + tx];
  __syncthreads();
  #pragma unroll
  for (int i = ty; i < 32; i += 8)
    Wt[(long)(nb + i) * K + kb + tx] = (__bf16)tile[tx][i];
}

// ---------------------------------------------------------------------------
// bf16 MFMA GEMM with global_load_lds staging (m97 structure).
// C(MxN) = A(MxK) @ Bt(NxK)^T. 128x128 block tile, 4 waves, 4x4 16x16 frags.
// LDS layout: unpadded [row][32k]; XOR chunk swizzle on the GLOBAL fetch
// (t = c ^ ((row>>1)&3)) so lane-contiguous LDS writes stay legal and
// ds_read_b128 fragment reads are 2-way (free).
// Block swizzle: flat&7 = XCD owns a contiguous y-strip, iterates x within,
// so the nxb blocks sharing an A row-tile hit the same per-XCD L2.
// mode 0: split bf16 epilogue (cols<768 -> C0 stride 768; else C1 stride 1536)
// mode 1: fp32 + bias epilogue into C0 stride N.
// grid: (M/128)*nxb blocks (1-D), (M/128)%8==0 required.
// ---------------------------------------------------------------------------
__global__ __launch_bounds__(256) void gemm_glds_kernel(
    const __bf16* __restrict__ A, const __bf16* __restrict__ Bt,
    void* __restrict__ C0, void* __restrict__ C1,
    const float* __restrict__ bias,
    int M, int N, int K, int nxb, int mode) {
  __shared__ __bf16 As[128 * 32];
  __shared__ __bf16 Bs[128 * 32];
  const int tid = threadIdx.x;
  const int wave = tid >> 6, lane = tid & 63;

  const int flat = blockIdx.x;
  const int xcd = flat & 7, rem = flat >> 3;
  const int per = (M >> 7) >> 3;           // y-tiles per XCD
  const int yb = xcd * per + rem / nxb;
  const int xb = rem % nxb;
  const long m0 = (long)yb * 128;
  const int n0 = xb * 128;

  const int wm = (wave >> 1) * 64, wn = (wave & 1) * 64;

  // staging: lane covers row (lane>>2) of the wave's 16-row slab, LDS chunk
  // (lane&3); fetches global chunk (lane&3)^((lane>>3)&3).
  const int srow = lane >> 2;
  const int gchunk = (lane & 3) ^ ((lane >> 3) & 3);
  const __bf16* Ag = A + (m0 + wave * 16 + srow) * (long)K + gchunk * 8;
  const __bf16* Bg = Bt + ((long)n0 + wave * 16 + srow) * (long)K + gchunk * 8;
  char* Al = (char*)As + wave * 16 * 64;   // + lane*16 applied by HW
  char* Bl = (char*)Bs + wave * 16 * 64;
  const long rowskip = 64 * (long)K;

  const int fr = lane & 15;
  const int csw = ((lane >> 4) ^ ((fr >> 1) & 3)) * 8;  // swizzled k-chunk (elems)

  floatx4 acc[4][4] = {};

  for (int k0 = 0; k0 < K; k0 += 32) {
    __syncthreads();
    gld16(Ag + k0, Al);
    gld16(Ag + k0 + rowskip, Al + 64 * 64);
    gld16(Bg + k0, Bl);
    gld16(Bg + k0 + rowskip, Bl + 64 * 64);
    __syncthreads();   // compiler drains vmcnt before s_barrier
    bf16x8 af[4], bfr[4];
    #pragma unroll
    for (int i = 0; i < 4; ++i)
      af[i] = *(const bf16x8*)&As[(wm + i * 16 + fr) * 32 + csw];
    #pragma unroll
    for (int j = 0; j < 4; ++j)
      bfr[j] = *(const bf16x8*)&Bs[(wn + j * 16 + fr) * 32 + csw];
    #pragma unroll
    for (int i = 0; i < 4; ++i)
      #pragma unroll
      for (int j = 0; j < 4; ++j)
        acc[i][j] = __builtin_amdgcn_mfma_f32_16x16x32_bf16(af[i], bfr[j], acc[i][j], 0, 0, 0);
  }

  const int col = lane & 15, rq = (lane >> 4) * 4;
  if (mode == 1) {
    #pragma unroll
    for (int i = 0; i < 4; ++i)
      #pragma unroll
      for (int j = 0; j < 4; ++j)
        #pragma unroll
        for (int r = 0; r < 4; ++r) {
          long gm = m0 + wm + i * 16 + rq + r;
          int gn = n0 + wn + j * 16 + col;
          ((float*)C0)[gm * N + gn] = acc[i][j][r] + bias[gn];
        }
  } else {
    // split: whole block is on one side of col 768 (n0 multiple of 128)
    if (n0 + 128 <= CDIM) {
      #pragma unroll
      for (int i = 0; i < 4; ++i)
        #pragma unroll
        for (int j = 0; j < 4; ++j)
          #pragma unroll
          for (int r = 0; r < 4; ++r) {
            long gm = m0 + wm + i * 16 + rq + r;
            int gn = n0 + wn + j * 16 + col;
            ((__bf16*)C0)[gm * CDIM + gn] = (__bf16)acc[i][j][r];
          }
    } else {
      #pragma unroll
      for (int i = 0; i < 4; ++i)
        #pragma unroll
        for (int j = 0; j < 4; ++j)
          #pragma unroll
          for (int r = 0; r < 4; ++r) {
            long gm = m0 + wm + i * 16 + rq + r;
            int gn = n0 + wn + j * 16 + col - CDIM;
            ((__bf16*)C1)[gm * EDIM + gn] = (__bf16)acc[i][j][r];
          }
    }
  }
}

// ---------------------------------------------------------------------------
// softmax over head_dim (64) on the k half of kv, in place.
// one wave per (token-row, head). grid: TOTTOK*NHEADS/4 blocks of 256.
// ---------------------------------------------------------------------------
__global__ __launch_bounds__(256) void softmax64_kernel(__bf16* __restrict__ kv) {
  long gid = (long)blockIdx.x * 4 + (threadIdx.x >> 6);
  int lane = threadIdx.x & 63;
  long row = gid / NHEADS;
  int h = (int)(gid % NHEADS);
  __bf16* p = kv + row * EDIM + h * HD;
  float v = (float)p[lane];
  float mx = v;
  #pragma unroll
  for (int m = 32; m; m >>= 1) mx = fmaxf(mx, __shfl_xor(mx, m));
  float e = __expf(v - mx);
  float s = e;
  #pragma unroll
  for (int m = 32; m; m >>= 1) s += __shfl_xor(s, m);
  p[lane] = (__bf16)(e / s);
}

// ---------------------------------------------------------------------------
// ktv partials: ktv_part[split][b][h][d][e] = sum_{n in split} ks[b,n,h,d]*v[b,n,h,e]
// grid: (4, NHEADS, NB), block 256 (4 waves, each 16 d-rows x 64 e-cols)
// ---------------------------------------------------------------------------
__global__ __launch_bounds__(256) void ktv_kernel(
    const __bf16* __restrict__ kv, float* __restrict__ ktv_part) {
  const int split = blockIdx.x, h = blockIdx.y, b = blockIdx.z;
  __shared__ __bf16 As[64 * 40];  // [d][n_local]
  __shared__ __bf16 Bs[64 * 40];  // [e][n_local]
  const int tid = threadIdx.x, wave = tid >> 6, lane = tid & 63;
  const int sn = tid >> 3;        // 0..31
  const int sc = (tid & 7) * 8;   // 0..56
  const int fr = lane & 15, fk = (lane >> 4) * 8;
  floatx4 acc[4] = {};
  const long rowbase = (long)b * NTOK * EDIM;

  for (int n0 = split * 1024; n0 < split * 1024 + 1024; n0 += 32) {
    __syncthreads();
    const __bf16* krow = kv + rowbase + (long)(n0 + sn) * EDIM + h * HD + sc;
    const __bf16* vrow = krow + CDIM;
    uint4 ku = *(const uint4*)krow;
    uint4 vu = *(const uint4*)vrow;
    const __bf16* kh = (const __bf16*)&ku;
    const __bf16* vh = (const __bf16*)&vu;
    #pragma unroll
    for (int j = 0; j < 8; ++j) {
      As[(sc + j) * 40 + sn] = kh[j];
      Bs[(sc + j) * 40 + sn] = vh[j];
    }
    __syncthreads();
    bf16x8 af = *(const bf16x8*)&As[(wave * 16 + fr) * 40 + fk];
    #pragma unroll
    for (int j = 0; j < 4; ++j) {
      bf16x8 bf_ = *(const bf16x8*)&Bs[(j * 16 + fr) * 40 + fk];
      acc[j] = __builtin_amdgcn_mfma_f32_16x16x32_bf16(af, bf_, acc[j], 0, 0, 0);
    }
  }

  const int col = lane & 15, rq = (lane >> 4) * 4;
  long base = (((long)split * NB + b) * NHEADS + h) * (HD * HD);
  #pragma unroll
  for (int j = 0; j < 4; ++j)
    #pragma unroll
    for (int r = 0; r < 4; ++r)
      ktv_part[base + (wave * 16 + rq + r) * HD + j * 16 + col] = acc[j][r];
}

// ---------------------------------------------------------------------------
// Build expanded ektv (bf16, [b][H][d][e], H in [0,24)) from the 4 partials,
// applying the head-expansion roll on the flattened (h*64+e) axis.
// ---------------------------------------------------------------------------
__global__ __launch_bounds__(256) void ektv_kernel(
    const float* __restrict__ ktv_part, __bf16* __restrict__ ektv) {
  int idx = blockIdx.x * 256 + threadIdx.x;  // < 8*24*64*64 = 786432
  int e = idx & 63;
  int d = (idx >> 6) & 63;
  int H = (idx >> 12) % 24;
  int b = idx / 98304;
  int c = H * 64 + e;
  int cp = (c < CDIM) ? c : (c - CDIM + 32) % CDIM;
  int hs = cp >> 6, es = cp & 63;
  long o = (((long)b * NHEADS + hs) * HD + d) * HD + es;
  float s = 0.f;
  #pragma unroll
  for (int sp = 0; sp < 4; ++sp)
    s += ktv_part[(long)sp * (NB * NHEADS * HD * HD) + o];
  ektv[idx] = (__bf16)s;
}

// ---------------------------------------------------------------------------
// attn: mid[b, n, H*64+e] = scale * sum_d eq[b,H,n,d] * ektv[b,H,d,e]
// eq columns for head H are q columns (qbase..qbase+63) mod 768.
// grid: (NTOK/128, 24, NB), block 256 (4 waves x 32 token rows).
// ---------------------------------------------------------------------------
__global__ __launch_bounds__(256) void attn_kernel(
    const __bf16* __restrict__ q, const __bf16* __restrict__ ektv,
    __bf16* __restrict__ mid) {
  const int tt = blockIdx.x, H = blockIdx.y, b = blockIdx.z;
  __shared__ __bf16 As[128 * 72];  // [n_local][d]
  __shared__ __bf16 Bs[64 * 72];   // [e][d]
  const int tid = threadIdx.x, wave = tid >> 6, lane = tid & 63;
  const int qbase = (H < NHEADS) ? H * 64 : (H - NHEADS) * 64 + 32;
  const long n0 = (long)b * NTOK + tt * 128;

  {  // stage A (q slice, handling the circular roll per 8-wide chunk)
    int nl = tid >> 1, d0 = (tid & 1) * 32;
    const __bf16* qrow = q + (n0 + nl) * CDIM;
    #pragma unroll
    for (int cch = 0; cch < 4; ++cch) {
      int d = d0 + cch * 8;
      int c0 = qbase + d;
      if (c0 >= CDIM) c0 -= CDIM;
      *(uint4*)&As[nl * 72 + d] = *(const uint4*)(qrow + c0);
    }
  }
  {  // stage B transposed: Bs[e][d] = ektv[b][H][d][e]
    int e = tid & 63, dch = (tid >> 6) * 16;
    const __bf16* src = ektv + ((long)b * 24 + H) * (HD * HD);
    alignas(16) __bf16 tmp[16];
    #pragma unroll
    for (int j = 0; j < 16; ++j) tmp[j] = src[(dch + j) * 64 + e];
    *(uint4*)&Bs[e * 72 + dch] = *(const uint4*)&tmp[0];
    *(uint4*)&Bs[e * 72 + dch + 8] = *(const uint4*)&tmp[8];
  }
  __syncthreads();

  floatx4 acc[2][4] = {};
  const int fr = lane & 15, fk = (lane >> 4) * 8;
  const int wm = wave * 32;
  #pragma unroll
  for (int kk = 0; kk < 64; kk += 32) {
    bf16x8 af0 = *(const bf16x8*)&As[(wm + fr) * 72 + kk + fk];
    bf16x8 af1 = *(const bf16x8*)&As[(wm + 16 + fr) * 72 + kk + fk];
    #pragma unroll
    for (int j = 0; j < 4; ++j) {
      bf16x8 bf_ = *(const bf16x8*)&Bs[(j * 16 + fr) * 72 + kk + fk];
      acc[0][j] = __builtin_amdgcn_mfma_f32_16x16x32_bf16(af0, bf_, acc[0][j], 0, 0, 0);
      acc[1][j] = __builtin_amdgcn_mfma_f32_16x16x32_bf16(af1, bf_, acc[1][j], 0, 0, 0);
    }
  }

  const int col = lane & 15, rq = (lane >> 4) * 4;
  const float scale = 0.125f;  // HEAD_DIM^-0.5
  #pragma unroll
  for (int i = 0; i < 2; ++i)
    #pragma unroll
    for (int j = 0; j < 4; ++j)
      #pragma unroll
      for (int r = 0; r < 4; ++r) {
        long n = n0 + wm + i * 16 + rq + r;
        mid[n * EDIM + H * 64 + j * 16 + col] = (__bf16)(acc[i][j][r] * scale);
      }
}

// ---------------------------------------------------------------------------
// LePE depthwise 3x3 conv, tiled through LDS.
// grid: (12 ch-groups of 64 q-channels, 16 y-groups of 4 rows, NB).
// ---------------------------------------------------------------------------
__global__ __launch_bounds__(256) void lepe_kernel(
    const __bf16* __restrict__ q, const float* __restrict__ w_lepe,
    const float* __restrict__ b_lepe, __bf16* __restrict__ mid) {
  __shared__ __bf16 smem[6 * 64 * 64];  // [row][x][ch], 48 KB
  const int g = blockIdx.x, yg = blockIdx.y, b = blockIdx.z;
  const int y0 = yg * 4;
  const int tid = threadIdx.x;

  #pragma unroll
  for (int k = 0; k < 12; ++k) {
    int v = tid + k * 256;            // 0..3071
    int r = v >> 9;                   // row in slab, 0..5
    int rem = v & 511;
    int x = rem >> 3;
    int chv = (rem & 7) * 8;
    int yy = y0 + r - 1;
    uint4 val = {0u, 0u, 0u, 0u};
    if (yy >= 0 && yy < 64)
      val = *(const uint4*)(q + ((long)(b * NTOK + yy * 64 + x)) * CDIM + g * 64 + chv);
    *(uint4*)&smem[r * 4096 + x * 64 + chv] = val;
  }
  __syncthreads();

  const int ch = tid & 63, xg = tid >> 6;
  const int cq = g * 64 + ch;                 // expanded channel (identity half)
  const int c2 = CDIM + ((cq + 736) % CDIM);  // rolled duplicate channel
  float w1[9], w2[9];
  #pragma unroll
  for (int j = 0; j < 9; ++j) {
    w1[j] = w_lepe[cq * 9 + j];
    w2[j] = w_lepe[c2 * 9 + j];
  }
  const float bias1 = b_lepe[cq], bias2 = b_lepe[c2];

  for (int ly = 0; ly < 4; ++ly) {
    for (int i = 0; i < 16; ++i) {
      int x = xg * 16 + i;
      float a1 = bias1, a2 = bias2;
      #pragma unroll
      for (int r = 0; r < 3; ++r) {
        #pragma unroll
        for (int dx = 0; dx < 3; ++dx) {
          int xx = x + dx - 1;
          if (xx < 0 || xx > 63) continue;  // wave-uniform (xg uniform per wave)
          float v = (float)smem[(ly + r) * 4096 + xx * 64 + ch];
          a1 += w1[r * 3 + dx] * v;
          a2 += w2[r * 3 + dx] * v;
        }
      }
      long o = ((long)(b * NTOK + (y0 + ly) * 64 + x)) * EDIM;
      mid[o + cq] = (__bf16)((float)mid[o + cq] + a1);
      mid[o + c2] = (__bf16)((float)mid[o + c2] + a2);
    }
  }
}

// ---------------------------------------------------------------------------
// launch
// ---------------------------------------------------------------------------
extern "C" void kernel_launch(void* const* d_in, const int* in_sizes, int n_in,
                              void* d_out, int out_size, void* d_ws, size_t ws_size,
                              hipStream_t stream) {
  const float* x      = (const float*)d_in[0];
  const float* w_q    = (const float*)d_in[1];
  const float* w_kv   = (const float*)d_in[2];
  const float* w_proj = (const float*)d_in[3];
  const float* b_proj = (const float*)d_in[4];
  const float* w_lepe = (const float*)d_in[5];
  const float* b_lepe = (const float*)d_in[6];
  float* out = (float*)d_out;

  char* ws = (char*)d_ws;
  __bf16* Wt_qkv = (__bf16*)ws; ws += (long)(CDIM + EDIM) * CDIM * 2;  // 2304x768 (NxK)
  __bf16* Wt_p   = (__bf16*)ws; ws += (long)CDIM * EDIM * 2;           // 768x1536 (NxK)
  __bf16* xb     = (__bf16*)ws; ws += (long)TOTTOK * CDIM * 2;
  __bf16* qb     = (__bf16*)ws; ws += (long)TOTTOK * CDIM * 2;
  __bf16* kvb    = (__bf16*)ws; ws += (long)TOTTOK * EDIM * 2;         // later aliased as mid
  float*  ktv_part = (float*)ws; ws += (long)4 * NB * NHEADS * HD * HD * 4;
  __bf16* ektv   = (__bf16*)ws; ws += (long)NB * 24 * HD * HD * 2;
  __bf16* mid = kvb;  // alias: kv is dead once ektv is built

  // 1. x -> bf16
  f32_to_bf16_kernel<<<(TOTTOK * CDIM) / (256 * 4), 256, 0, stream>>>(
      x, xb, (long)TOTTOK * CDIM);
  // 2. weight transposes (K x N fp32 -> N x K bf16), q|kv concatenated
  transpose_w_kernel<<<dim3(CDIM / 32, CDIM / 32), 256, 0, stream>>>(
      w_q, Wt_qkv, CDIM, CDIM);
  transpose_w_kernel<<<dim3(EDIM / 32, CDIM / 32), 256, 0, stream>>>(
      w_kv, Wt_qkv + (long)CDIM * CDIM, CDIM, EDIM);
  transpose_w_kernel<<<dim3(CDIM / 32, EDIM / 32), 256, 0, stream>>>(
      w_proj, Wt_p, EDIM, CDIM);
  // 3. fused qkv = x @ [w_q | w_kv]  (split epilogue -> qb, kvb)
  gemm_glds_kernel<<<(TOTTOK / 128) * 18, 256, 0, stream>>>(
      xb, Wt_qkv, qb, kvb, nullptr, TOTTOK, CDIM + EDIM, CDIM, 18, 0);
  // 4. softmax over head_dim on k half, in place
  softmax64_kernel<<<(TOTTOK * NHEADS) / 4, 256, 0, stream>>>(kvb);
  // 5. ktv partials (split-K over tokens)
  ktv_kernel<<<dim3(4, NHEADS, NB), 256, 0, stream>>>(kvb, ktv_part);
  // 6. reduce partials + head-expand -> ektv
  ektv_kernel<<<(NB * 24 * HD * HD) / 256, 256, 0, stream>>>(ktv_part, ektv);
  // 7. attn -> mid (overwrites kv buffer)
  attn_kernel<<<dim3(NTOK / 128, 24, NB), 256, 0, stream>>>(qb, ektv, mid);
  // 8. mid += lepe (tiled, LDS-staged)
  lepe_kernel<<<dim3(12, 16, NB), 256, 0, stream>>>(qb, w_lepe, b_lepe, mid);
  // 9. out = mid @ w_proj + b_proj (fp32 out, XCD-swizzled)
  gemm_glds_kernel<<<(TOTTOK / 128) * 6, 256, 0, stream>>>(
      mid, Wt_p, out, nullptr, b_proj, TOTTOK, CDIM, EDIM, 6, 1);
}